// Round 12
// baseline (277.099 us; speedup 1.0000x reference)
//
#include <hip/hip_runtime.h>

// out[b,c,n,f] = W[f, x[b,c,n]] + b[f]  -> 256 MiB fp32 write, gather from a
// transposed bias-folded 1 MiB table (L2-resident).
// Measured floor context: dur_us includes harness poison fills
// (1.074 GB d_ws ~165us + 268 MB d_out ~41us = ~206us fixed). Our kernels:
// R2 ~81us (MLP=1) -> R7 ~62us (MLP=8). Floor ~53us (41 write + 8 build + launches).
#define VOCAB   4096
#define F_DIM   64
#define TOKENS  (32 * 16 * 2048)

typedef float f32x4 __attribute__((ext_vector_type(4)));

// Build WT[v][f] = W[f][v] + b[f] with BOTH sides coalesced via LDS tile.
// 64 blocks, each does a 64f x 64v tile. float4 loads along v, float4
// stores along f. Pad LDS row by 1 float4 to dodge bank conflicts.
__global__ void __launch_bounds__(256)
build_wt_kernel(const f32x4* __restrict__ W4,   // W viewed as [64][1024] float4
                const float* __restrict__ bias,
                f32x4* __restrict__ WT4) {      // WT viewed as [4096][16] float4
    __shared__ f32x4 tile[F_DIM][17];           // [f][v4], 16+1 pad
    const int t  = threadIdx.x;                 // 0..255
    const int v0 = blockIdx.x * F_DIM;          // this block's v range

    // Load: thread t -> f = t>>4 (+16 per iter), v4 = t&15. Consecutive t
    // covers 16 consecutive float4 of one W row -> coalesced 256 B bursts.
    #pragma unroll
    for (int i = 0; i < 4; ++i) {
        int f  = i * 16 + (t >> 4);
        int v4 = t & 15;
        tile[f][v4] = W4[f * (VOCAB / 4) + (v0 >> 2) + v4];
    }
    __syncthreads();

    // Store: thread t -> dv = t>>4 (+16 per iter), f4 = t&15. Consecutive t
    // covers one WT row (16 float4 = 256 B) -> coalesced.
    #pragma unroll
    for (int i = 0; i < 4; ++i) {
        int dv = i * 16 + (t >> 4);
        int f4 = t & 15;
        int f  = f4 * 4;
        // gather 4 f-values for this dv from the tile (column read, padded)
        f32x4 r;
        r.x = tile[f + 0][dv >> 2][dv & 3] + bias[f + 0];
        r.y = tile[f + 1][dv >> 2][dv & 3] + bias[f + 1];
        r.z = tile[f + 2][dv >> 2][dv & 3] + bias[f + 2];
        r.w = tile[f + 3][dv >> 2][dv & 3] + bias[f + 3];
        WT4[(v0 + dv) * 16 + f4] = r;
    }
}

// Gather, MLP=8, block-local chains: block covers 2048 consecutive float4s
// (= 128 consecutive tokens, 32 KiB contiguous output). Each thread owns 8
// fragments 256 apart -> 8 independent idx->WT->out chains; every wave-store
// is 1 KiB contiguous; all 8 spans of a block sit in one 32 KiB region.
__global__ void __launch_bounds__(256)
gather_kernel(const int* __restrict__ idx,
              const f32x4* __restrict__ WT4,
              f32x4* __restrict__ out4) {
    const unsigned base = blockIdx.x * 2048u + threadIdx.x;

    unsigned i[8];
    #pragma unroll
    for (int k = 0; k < 8; ++k) i[k] = base + (unsigned)k * 256u;

    int id[8];
    #pragma unroll
    for (int k = 0; k < 8; ++k) id[k] = idx[i[k] >> 4];

    f32x4 v[8];
    #pragma unroll
    for (int k = 0; k < 8; ++k)
        v[k] = WT4[(unsigned)id[k] * 16u + (i[k] & 15u)];

    #pragma unroll
    for (int k = 0; k < 8; ++k) out4[i[k]] = v[k];
}

extern "C" void kernel_launch(void* const* d_in, const int* in_sizes, int n_in,
                              void* d_out, int out_size, void* d_ws, size_t ws_size,
                              hipStream_t stream) {
    const int*   x = (const int*)d_in[0];
    const float* W = (const float*)d_in[1];
    const float* b = (const float*)d_in[2];
    float* out = (float*)d_out;
    float* WT  = (float*)d_ws;   // 1 MiB scratch

    build_wt_kernel<<<VOCAB / F_DIM, 256, 0, stream>>>((const f32x4*)W, b,
                                                       (f32x4*)WT);

    // 8192 blocks x 256 thr x 8 float4 = 16,777,216 fragments (exact cover).
    gather_kernel<<<8192, 256, 0, stream>>>(x, (const f32x4*)WT, (f32x4*)out);
}

// Round 13
// 270.870 us; speedup vs baseline: 1.0230x; 1.0230x over previous
//
#include <hip/hip_runtime.h>

// EXACT resubmission of the R7 kernel (best measured: 268.4 us) as an A/B
// reproducibility check against R12's 277.1 (LDS build + block-local gather
// regressed or noise; fills alone carry +-6us of run-to-run noise).
// Budget: dur_us = ~207us harness poison fills (untouchable) + ours.
// Ours (R7): ~61us. Floor: ~50us (41 write + ~6 build + launches).
#define VOCAB   4096
#define F_DIM   64
#define TOKENS  (32 * 16 * 2048)

typedef float f32x4 __attribute__((ext_vector_type(4)));

// Build WT[v][f] = W[f][v] + b[f].  65,536 threads = 256 blocks.
// Reads: 4 coalesced streams (consecutive lanes -> consecutive v).
// Writes: 16 B per thread at 256 B stride -> imperfect but only 1 MiB total.
__global__ void build_wt_kernel(const float* __restrict__ W,
                                const float* __restrict__ bias,
                                f32x4* __restrict__ WT4) {
    int k  = blockIdx.x * blockDim.x + threadIdx.x;   // 0..65535
    int f4 = k >> 12;                                 // 0..15
    int v  = k & (VOCAB - 1);
    int f  = f4 * 4;
    f32x4 r;
    r.x = W[(f + 0) * VOCAB + v] + bias[f + 0];
    r.y = W[(f + 1) * VOCAB + v] + bias[f + 1];
    r.z = W[(f + 2) * VOCAB + v] + bias[f + 2];
    r.w = W[(f + 3) * VOCAB + v] + bias[f + 3];
    WT4[v * 16 + f4] = r;
}

// Gather. Fragment = one float4 (16 B); 16 fragments per token.
// 16,777,216 fragments; each thread owns 8, spaced nth apart ->
// 8 INDEPENDENT idx->WT->out chains (MLP=8).
// Fully-unrolled arrays => static register indexing (no scratch).
// Every wave-store instr: 64 consecutive float4 = 1 KiB contiguous.
__global__ void __launch_bounds__(256)
gather_kernel(const int* __restrict__ idx,
              const f32x4* __restrict__ WT4,
              f32x4* __restrict__ out4) {
    const unsigned nth = gridDim.x * blockDim.x;      // 2,097,152
    const unsigned tid = blockIdx.x * blockDim.x + threadIdx.x;

    unsigned i[8];
    #pragma unroll
    for (int k = 0; k < 8; ++k) i[k] = tid + (unsigned)k * nth;

    // All idx loads issued first (independent; 16 lanes share one token).
    int id[8];
    #pragma unroll
    for (int k = 0; k < 8; ++k) id[k] = idx[i[k] >> 4];

    // All WT gathers issued next (independent of each other).
    f32x4 v[8];
    #pragma unroll
    for (int k = 0; k < 8; ++k)
        v[k] = WT4[(unsigned)id[k] * 16u + (i[k] & 15u)];

    // Coalesced stores.
    #pragma unroll
    for (int k = 0; k < 8; ++k) out4[i[k]] = v[k];
}

extern "C" void kernel_launch(void* const* d_in, const int* in_sizes, int n_in,
                              void* d_out, int out_size, void* d_ws, size_t ws_size,
                              hipStream_t stream) {
    const int*   x = (const int*)d_in[0];
    const float* W = (const float*)d_in[1];
    const float* b = (const float*)d_in[2];
    float* out = (float*)d_out;
    float* WT  = (float*)d_ws;   // 1 MiB scratch

    build_wt_kernel<<<256, 256, 0, stream>>>(W, b, (f32x4*)WT);

    // 8192 blocks x 256 thr; 8 float4 fragments per thread (exact cover).
    gather_kernel<<<8192, 256, 0, stream>>>(x, (const f32x4*)WT, (f32x4*)out);
}